// Round 13
// baseline (361.226 us; speedup 1.0000x reference)
//
#include <hip/hip_runtime.h>

using short8  = __attribute__((ext_vector_type(8))) short;
using f32x4   = __attribute__((ext_vector_type(4))) float;
using uint32x4 = __attribute__((ext_vector_type(4))) unsigned;

static constexpr int N_NODES = 100000;
static constexpr int N_EDGES = 3200000;
static constexpr int IN_DIM  = 512;
static constexpr int OUT_DIM = 128;
static constexpr int NBINS   = (N_NODES + 255) / 256;  // 391 bins of 256 nodes
static constexpr int NB      = 1024;                   // binning blocks
static constexpr int CHUNK   = N_EDGES / NB;           // 3125 edges/block (exact)

__device__ __forceinline__ short f2bf(float f) {
  unsigned u = __builtin_bit_cast(unsigned, f);
  u = (u + 0x7FFFu + ((u >> 16) & 1u)) >> 16;  // RNE
  return (short)u;
}

// ---- W [512][128] f32 -> k-blocked bf16: WTb[ks][c][lk][j]  (ks=k>>5) ----
__global__ __launch_bounds__(256) void cast_WT(const float* __restrict__ W,
                                               short* __restrict__ WTb) {
  const int idx = blockIdx.x * 256 + threadIdx.x;  // 65536 total
  const int k = idx >> 7, c = idx & 127;
  const int ks = k >> 5, lk = (k >> 3) & 3, j = k & 7;
  WTb[(size_t)((ks * 128 + c) * 4 + lk) * 8 + j] = f2bf(W[(size_t)k * 128 + c]);
}

// ---------------- direct-from-global MFMA GEMM: xwb = (x@W)*dinv ----------
// Output layout: slice-major xwb[slice=cf][node][16]  (3.2MB per slice)
__global__ __launch_bounds__(256, 4) void gemm_direct(const float* __restrict__ x,
                                                      const short* __restrict__ WTb,
                                                      const float* __restrict__ dinv,
                                                      unsigned short* __restrict__ xwb) {
  const int tid = threadIdx.x;
  const int w   = tid >> 6;
  const int l   = tid & 63;
  const int lr  = l & 15;   // A row within fragment / B col within cf
  const int lk  = l >> 4;   // k-subchunk
  const int row0 = blockIdx.x * 64 + w * 16;

  const int ra = min(row0 + lr, N_NODES - 1);  // clamp; masked at write
  const float* pa = &x[(size_t)ra * IN_DIM + lk * 8];
  const char*  wb = reinterpret_cast<const char*>(WTb) + lr * 64 + lk * 16;

  f32x4 acc[8] = {};

  float4 A0[2], A1[2];
  short8 B[2][8];

  auto loadA = [&](int ks, int s) {
    const float* p = pa + ks * 32;
    A0[s] = *reinterpret_cast<const float4*>(p);
    A1[s] = *reinterpret_cast<const float4*>(p + 4);
  };
  auto loadB = [&](int ks, int s) {
    const char* base = wb + ks * 8192;
#pragma unroll
    for (int cf = 0; cf < 8; ++cf)
      B[s][cf] = *reinterpret_cast<const short8*>(base + cf * 1024);
  };
  auto cvt2 = [](float lo, float hi) -> unsigned {
    unsigned r;
    asm("v_cvt_pk_bf16_f32 %0, %1, %2" : "=v"(r) : "v"(lo), "v"(hi));
    return r;
  };
  auto compute = [&](int s) {
    uint32x4 ua;
    ua[0] = cvt2(A0[s].x, A0[s].y);
    ua[1] = cvt2(A0[s].z, A0[s].w);
    ua[2] = cvt2(A1[s].x, A1[s].y);
    ua[3] = cvt2(A1[s].z, A1[s].w);
    const short8 a = __builtin_bit_cast(short8, ua);
#pragma unroll
    for (int cf = 0; cf < 8; ++cf)
      acc[cf] = __builtin_amdgcn_mfma_f32_16x16x32_bf16(a, B[s][cf], acc[cf], 0, 0, 0);
  };

  loadA(0, 0);
  loadB(0, 0);

#pragma unroll
  for (int kp = 0; kp < 8; ++kp) {
    const int ks = kp * 2;
    loadA(ks + 1, 1);
    loadB(ks + 1, 1);
    compute(0);
    if (kp < 7) {
      loadA(ks + 2, 0);
      loadB(ks + 2, 0);
    }
    compute(1);
  }

  // C/D: col = cf*16 + lr, row = lk*4 + j.  Store slice-major: [cf][row][lr]
#pragma unroll
  for (int j = 0; j < 4; ++j) {
    const int row = row0 + lk * 4 + j;
    if (row < N_NODES) {
      const float sc = dinv[row];  // prescale: xwb = xw * dinv[row]
#pragma unroll
      for (int cf = 0; cf < 8; ++cf)
        xwb[((size_t)cf * N_NODES + row) * 16 + lr] =
            (unsigned short)f2bf(acc[cf][j] * sc);
    }
  }
}

// ========== atomic-free edge grouping: 2-level binning, LDS-only atomics ====

// A1: per-block LDS histogram of bin = col>>8
__global__ __launch_bounds__(256) void bin_count(const int* __restrict__ ecol,
                                                 int* __restrict__ blkhist) {
  __shared__ int hist[NBINS];
  const int blk = blockIdx.x, tid = threadIdx.x;
  for (int i = tid; i < NBINS; i += 256) hist[i] = 0;
  __syncthreads();
  const int e0 = blk * CHUNK, e1 = e0 + CHUNK;
  for (int e = e0 + tid; e < e1; e += 256) atomicAdd(&hist[ecol[e] >> 8], 1);
  __syncthreads();
  for (int i = tid; i < NBINS; i += 256) blkhist[(size_t)blk * NBINS + i] = hist[i];
}

// A2a: per-bin exclusive scan over the NB block partials (in place)
__global__ __launch_bounds__(1024) void scan_blkhist(int* __restrict__ blkhist,
                                                     int* __restrict__ bintot) {
  __shared__ int sh[NB];
  const int bin = blockIdx.x, t = threadIdx.x;
  const int v = blkhist[(size_t)t * NBINS + bin];
  sh[t] = v;
  __syncthreads();
  for (int d = 1; d < NB; d <<= 1) {
    const int tv = (t >= d) ? sh[t - d] : 0;
    __syncthreads();
    sh[t] += tv;
    __syncthreads();
  }
  blkhist[(size_t)t * NBINS + bin] = sh[t] - v;  // exclusive prefix over blocks
  if (t == NB - 1) bintot[bin] = sh[t];
}

// A2b: exclusive scan over bin totals
__global__ __launch_bounds__(512) void scan_bins(const int* __restrict__ bintot,
                                                 int* __restrict__ binbase) {
  __shared__ int sh[512];
  const int t = threadIdx.x;
  const int v = (t < NBINS) ? bintot[t] : 0;
  sh[t] = v;
  __syncthreads();
  for (int d = 1; d < 512; d <<= 1) {
    const int tv = (t >= d) ? sh[t - d] : 0;
    __syncthreads();
    sh[t] += tv;
    __syncthreads();
  }
  if (t < NBINS) binbase[t] = sh[t] - v;
  if (t == NBINS - 1) binbase[NBINS] = sh[t];
}

// A3: scatter packed (local_col<<24 | row) into bin-segmented benc
__global__ __launch_bounds__(256) void bin_scatter(const int* __restrict__ erow,
                                                   const int* __restrict__ ecol,
                                                   const int* __restrict__ blkhist,
                                                   const int* __restrict__ binbase,
                                                   unsigned* __restrict__ benc) {
  __shared__ int cur[NBINS];
  const int blk = blockIdx.x, tid = threadIdx.x;
  for (int i = tid; i < NBINS; i += 256)
    cur[i] = binbase[i] + blkhist[(size_t)blk * NBINS + i];
  __syncthreads();
  const int e0 = blk * CHUNK, e1 = e0 + CHUNK;
  for (int e = e0 + tid; e < e1; e += 256) {
    const int c = ecol[e];
    const unsigned enc = (unsigned)erow[e] | ((unsigned)(c & 255) << 24);
    const int p = atomicAdd(&cur[c >> 8], 1);
    benc[p] = enc;
  }
}

// B: per-bin CSR build — offs, dinv, brow (one block per 256-node bin)
__global__ __launch_bounds__(256) void bin_build(const unsigned* __restrict__ benc,
                                                 const int* __restrict__ binbase,
                                                 int* __restrict__ brow,
                                                 int* __restrict__ offs,
                                                 float* __restrict__ dinv) {
  __shared__ int hist[256];
  __shared__ int sh[256];
  __shared__ int cur[256];
  const int b = blockIdx.x, tid = threadIdx.x;
  const int e0 = binbase[b], e1 = binbase[b + 1];
  hist[tid] = 0;
  __syncthreads();
  for (int e = e0 + tid; e < e1; e += 256) atomicAdd(&hist[benc[e] >> 24], 1);
  __syncthreads();
  const int d0 = hist[tid];
  sh[tid] = d0;
  __syncthreads();
  for (int d = 1; d < 256; d <<= 1) {
    const int tv = (tid >= d) ? sh[tid - d] : 0;
    __syncthreads();
    sh[tid] += tv;
    __syncthreads();
  }
  const int myoff = e0 + sh[tid] - d0;  // global CSR offset for node (b<<8)+tid
  cur[tid] = myoff;
  const int node = (b << 8) + tid;
  if (node < N_NODES) {
    offs[node] = myoff;
    dinv[node] = rsqrtf((float)d0 + 1.0f);
  }
  if (b == NBINS - 1 && tid == 255) offs[N_NODES] = e1;
  __syncthreads();
  for (int e = e0 + tid; e < e1; e += 256) {
    const unsigned v = benc[e];
    const int p = atomicAdd(&cur[v >> 24], 1);
    brow[p] = (int)(v & 0x00FFFFFFu);
  }
}

// ------- gather: XCD-sliced. slice = bid&7 -> same XCD (round-robin map). -
// Each slice reads only its 3.2MB xwb slice (L2-resident per XCD).
// Wave = 8 nodes x 8 lanes; per node-lane 2 cols of the 16-col slice.
__global__ __launch_bounds__(256) void gather_out(const unsigned short* __restrict__ xwb,
                                                  const float* __restrict__ dinv,
                                                  const int* __restrict__ offs,
                                                  const int* __restrict__ brow,
                                                  const float* __restrict__ bias,
                                                  float* __restrict__ out) {
  const int bid   = blockIdx.x;
  const int slice = bid & 7;
  const int chunk = bid >> 3;          // 0..3124
  const int tid   = threadIdx.x;
  const int wave  = tid >> 6;
  const int lane  = tid & 63;
  const int sub   = lane >> 3;         // node sub-group 0..7
  const int sl    = lane & 7;          // lane within sub-group
  const int node  = chunk * 32 + wave * 8 + sub;
  if (node >= N_NODES) return;

  const unsigned short* xs = xwb + (size_t)slice * N_NODES * 16;
  const float di = dinv[node];
  const int c0 = sl * 2;

  auto ld2 = [&](int r) -> float2 {
    const unsigned v = *reinterpret_cast<const unsigned*>(&xs[(size_t)r * 16 + c0]);
    float2 f;
    f.x = __builtin_bit_cast(float, v << 16);
    f.y = __builtin_bit_cast(float, v & 0xFFFF0000u);
    return f;
  };

  float2 acc = ld2(node);  // self-loop (prescaled)

  int e = offs[node];
  const int e1 = offs[node + 1];
  for (; e + 4 <= e1; e += 4) {
    const int r0 = brow[e], r1 = brow[e + 1], r2 = brow[e + 2], r3 = brow[e + 3];
    const float2 v0 = ld2(r0), v1 = ld2(r1), v2 = ld2(r2), v3 = ld2(r3);
    acc.x += (v0.x + v1.x) + (v2.x + v3.x);
    acc.y += (v0.y + v1.y) + (v2.y + v3.y);
  }
  for (; e < e1; ++e) {
    const float2 v = ld2(brow[e]);
    acc.x += v.x;
    acc.y += v.y;
  }

  const int oc = slice * 16 + c0;
  const float2 bb = *reinterpret_cast<const float2*>(&bias[oc]);
  float2 o;
  o.x = acc.x * di + bb.x;
  o.y = acc.y * di + bb.y;
  *reinterpret_cast<float2*>(&out[(size_t)node * OUT_DIM + oc]) = o;
}

extern "C" void kernel_launch(void* const* d_in, const int* in_sizes, int n_in,
                              void* d_out, int out_size, void* d_ws, size_t ws_size,
                              hipStream_t stream) {
  const float* x    = (const float*)d_in[0];
  const int*   eidx = (const int*)d_in[1];
  const float* W    = (const float*)d_in[2];
  const float* b    = (const float*)d_in[3];
  float* out = (float*)d_out;

  const int* erow = eidx;            // sources
  const int* ecol = eidx + N_EDGES;  // destinations

  char* ws = (char*)d_ws;
  size_t off = 0;
  auto alloc = [&](size_t bytes) -> void* {
    void* p = ws + off;
    off = (off + bytes + 255) & ~(size_t)255;
    return p;
  };
  unsigned short* xwb = (unsigned short*)alloc((size_t)8 * N_NODES * 16 * sizeof(short)); // 25.6MB
  short* WTb     = (short*)alloc((size_t)OUT_DIM * IN_DIM * sizeof(short));    // 128KB
  float* dinv    = (float*)alloc((size_t)N_NODES * sizeof(float));             // 400KB
  int*   offs    = (int*)alloc((size_t)(N_NODES + 1) * sizeof(int));           // 400KB
  int*   blkhist = (int*)alloc((size_t)NB * NBINS * sizeof(int));              // 1.6MB
  int*   bintot  = (int*)alloc((size_t)NBINS * sizeof(int));
  int*   binbase = (int*)alloc((size_t)(NBINS + 1) * sizeof(int));
  int*   brow    = (int*)alloc((size_t)N_EDGES * sizeof(int));                 // 12.8MB
  unsigned* benc = (unsigned*)alloc((size_t)N_EDGES * sizeof(unsigned));       // 12.8MB

  cast_WT<<<256, 256, 0, stream>>>(W, WTb);

  bin_count<<<NB, 256, 0, stream>>>(ecol, blkhist);
  scan_blkhist<<<NBINS, NB, 0, stream>>>(blkhist, bintot);
  scan_bins<<<1, 512, 0, stream>>>(bintot, binbase);
  bin_scatter<<<NB, 256, 0, stream>>>(erow, ecol, blkhist, binbase, benc);
  bin_build<<<NBINS, 256, 0, stream>>>(benc, binbase, brow, offs, dinv);

  gemm_direct<<<(N_NODES + 63) / 64, 256, 0, stream>>>(x, WTb, dinv, xwb);
  gather_out<<<8 * ((N_NODES + 31) / 32), 256, 0, stream>>>(xwb, dinv, offs, brow, b, out);
}

// Round 15
// 309.986 us; speedup vs baseline: 1.1653x; 1.1653x over previous
//
#include <hip/hip_runtime.h>
#include <hip/hip_bf16.h>

using short8  = __attribute__((ext_vector_type(8))) short;
using f32x4   = __attribute__((ext_vector_type(4))) float;
using uint32x4 = __attribute__((ext_vector_type(4))) unsigned;

static constexpr int N_NODES = 100000;
static constexpr int N_EDGES = 3200000;
static constexpr int IN_DIM  = 512;
static constexpr int OUT_DIM = 128;
static constexpr int NBINS   = (N_NODES + 255) / 256;  // 391 bins of 256 nodes
static constexpr int NB      = 1024;                   // binning blocks
static constexpr int CHUNK   = N_EDGES / NB;           // 3125 edges/block (exact)

__device__ __forceinline__ short f2bf(float f) {
  unsigned u = __builtin_bit_cast(unsigned, f);
  u = (u + 0x7FFFu + ((u >> 16) & 1u)) >> 16;  // RNE
  return (short)u;
}

// ---- W [512][128] f32 -> k-blocked bf16: WTb[ks][c][lk][j]  (ks=k>>5) ----
__global__ __launch_bounds__(256) void cast_WT(const float* __restrict__ W,
                                               short* __restrict__ WTb) {
  const int idx = blockIdx.x * 256 + threadIdx.x;  // 65536 total
  const int k = idx >> 7, c = idx & 127;
  const int ks = k >> 5, lk = (k >> 3) & 3, j = k & 7;
  WTb[(size_t)((ks * 128 + c) * 4 + lk) * 8 + j] = f2bf(W[(size_t)k * 128 + c]);
}

// ---------------- direct-from-global MFMA GEMM: xwb = (x@W)*dinv ----------
// No LDS/barriers. Wave = 16 rows x 128 cols. Copy-free ping-pong A/B regs.
// f32->bf16 via compiler cvt_pk (no inline asm). NO VGPR cap.
__global__ __launch_bounds__(256) void gemm_direct(const float* __restrict__ x,
                                                   const short* __restrict__ WTb,
                                                   const float* __restrict__ dinv,
                                                   unsigned short* __restrict__ xwb) {
  const int tid = threadIdx.x;
  const int w   = tid >> 6;
  const int l   = tid & 63;
  const int lr  = l & 15;   // A row within fragment / B col within cf
  const int lk  = l >> 4;   // k-subchunk
  const int row0 = blockIdx.x * 64 + w * 16;

  const int ra = min(row0 + lr, N_NODES - 1);  // clamp; masked at write
  const float* pa = &x[(size_t)ra * IN_DIM + lk * 8];
  const char*  wb = reinterpret_cast<const char*>(WTb) + lr * 64 + lk * 16;

  f32x4 acc[8] = {};

  float4 A0[2], A1[2];
  short8 B[2][8];

  auto loadA = [&](int ks, int s) {
    const float* p = pa + ks * 32;
    A0[s] = *reinterpret_cast<const float4*>(p);
    A1[s] = *reinterpret_cast<const float4*>(p + 4);
  };
  auto loadB = [&](int ks, int s) {
    const char* base = wb + ks * 8192;
#pragma unroll
    for (int cf = 0; cf < 8; ++cf)
      B[s][cf] = *reinterpret_cast<const short8*>(base + cf * 1024);
  };
  auto cvt2 = [](float lo, float hi) -> unsigned {
    __hip_bfloat162 h = __float22bfloat162_rn(make_float2(lo, hi));
    unsigned r;
    __builtin_memcpy(&r, &h, 4);
    return r;
  };
  auto compute = [&](int s) {
    uint32x4 ua;
    ua[0] = cvt2(A0[s].x, A0[s].y);
    ua[1] = cvt2(A0[s].z, A0[s].w);
    ua[2] = cvt2(A1[s].x, A1[s].y);
    ua[3] = cvt2(A1[s].z, A1[s].w);
    const short8 a = __builtin_bit_cast(short8, ua);
#pragma unroll
    for (int cf = 0; cf < 8; ++cf)
      acc[cf] = __builtin_amdgcn_mfma_f32_16x16x32_bf16(a, B[s][cf], acc[cf], 0, 0, 0);
  };

  loadA(0, 0);
  loadB(0, 0);

#pragma unroll
  for (int kp = 0; kp < 8; ++kp) {
    const int ks = kp * 2;
    loadA(ks + 1, 1);
    loadB(ks + 1, 1);
    compute(0);
    if (kp < 7) {
      loadA(ks + 2, 0);
      loadB(ks + 2, 0);
    }
    compute(1);
  }

  // C/D: col = lane&15 (=lr within cf), row = (lane>>4)*4 + j (=lk*4+j)
#pragma unroll
  for (int j = 0; j < 4; ++j) {
    const int row = row0 + lk * 4 + j;
    if (row < N_NODES) {
      const float sc = dinv[row];  // prescale: xwb = xw * dinv[row]
      unsigned short* o = &xwb[(size_t)row * OUT_DIM + lr];
#pragma unroll
      for (int cf = 0; cf < 8; ++cf)
        o[cf * 16] = (unsigned short)f2bf(acc[cf][j] * sc);
    }
  }
}

// ========== atomic-free edge grouping: 2-level binning, LDS-only atomics ====

// A1: per-block LDS histogram of bin = col>>8
__global__ __launch_bounds__(256) void bin_count(const int* __restrict__ ecol,
                                                 int* __restrict__ blkhist) {
  __shared__ int hist[NBINS];
  const int blk = blockIdx.x, tid = threadIdx.x;
  for (int i = tid; i < NBINS; i += 256) hist[i] = 0;
  __syncthreads();
  const int e0 = blk * CHUNK, e1 = e0 + CHUNK;
  for (int e = e0 + tid; e < e1; e += 256) atomicAdd(&hist[ecol[e] >> 8], 1);
  __syncthreads();
  for (int i = tid; i < NBINS; i += 256) blkhist[(size_t)blk * NBINS + i] = hist[i];
}

// A2a: per-bin exclusive scan over the NB block partials (in place)
__global__ __launch_bounds__(1024) void scan_blkhist(int* __restrict__ blkhist,
                                                     int* __restrict__ bintot) {
  __shared__ int sh[NB];
  const int bin = blockIdx.x, t = threadIdx.x;
  const int v = blkhist[(size_t)t * NBINS + bin];
  sh[t] = v;
  __syncthreads();
  for (int d = 1; d < NB; d <<= 1) {
    const int tv = (t >= d) ? sh[t - d] : 0;
    __syncthreads();
    sh[t] += tv;
    __syncthreads();
  }
  blkhist[(size_t)t * NBINS + bin] = sh[t] - v;  // exclusive prefix over blocks
  if (t == NB - 1) bintot[bin] = sh[t];
}

// A2b: exclusive scan over bin totals
__global__ __launch_bounds__(512) void scan_bins(const int* __restrict__ bintot,
                                                 int* __restrict__ binbase) {
  __shared__ int sh[512];
  const int t = threadIdx.x;
  const int v = (t < NBINS) ? bintot[t] : 0;
  sh[t] = v;
  __syncthreads();
  for (int d = 1; d < 512; d <<= 1) {
    const int tv = (t >= d) ? sh[t - d] : 0;
    __syncthreads();
    sh[t] += tv;
    __syncthreads();
  }
  if (t < NBINS) binbase[t] = sh[t] - v;
  if (t == NBINS - 1) binbase[NBINS] = sh[t];
}

// A3: scatter packed (local_col<<24 | row) into bin-segmented benc
__global__ __launch_bounds__(256) void bin_scatter(const int* __restrict__ erow,
                                                   const int* __restrict__ ecol,
                                                   const int* __restrict__ blkhist,
                                                   const int* __restrict__ binbase,
                                                   unsigned* __restrict__ benc) {
  __shared__ int cur[NBINS];
  const int blk = blockIdx.x, tid = threadIdx.x;
  for (int i = tid; i < NBINS; i += 256)
    cur[i] = binbase[i] + blkhist[(size_t)blk * NBINS + i];
  __syncthreads();
  const int e0 = blk * CHUNK, e1 = e0 + CHUNK;
  for (int e = e0 + tid; e < e1; e += 256) {
    const int c = ecol[e];
    const unsigned enc = (unsigned)erow[e] | ((unsigned)(c & 255) << 24);
    const int p = atomicAdd(&cur[c >> 8], 1);
    benc[p] = enc;
  }
}

// B: per-bin CSR build — offs, dinv, brow (one block per 256-node bin)
__global__ __launch_bounds__(256) void bin_build(const unsigned* __restrict__ benc,
                                                 const int* __restrict__ binbase,
                                                 int* __restrict__ brow,
                                                 int* __restrict__ offs,
                                                 float* __restrict__ dinv) {
  __shared__ int hist[256];
  __shared__ int sh[256];
  __shared__ int cur[256];
  const int b = blockIdx.x, tid = threadIdx.x;
  const int e0 = binbase[b], e1 = binbase[b + 1];
  hist[tid] = 0;
  __syncthreads();
  for (int e = e0 + tid; e < e1; e += 256) atomicAdd(&hist[benc[e] >> 24], 1);
  __syncthreads();
  const int d0 = hist[tid];
  sh[tid] = d0;
  __syncthreads();
  for (int d = 1; d < 256; d <<= 1) {
    const int tv = (tid >= d) ? sh[tid - d] : 0;
    __syncthreads();
    sh[tid] += tv;
    __syncthreads();
  }
  const int myoff = e0 + sh[tid] - d0;  // global CSR offset for node (b<<8)+tid
  cur[tid] = myoff;
  const int node = (b << 8) + tid;
  if (node < N_NODES) {
    offs[node] = myoff;
    dinv[node] = rsqrtf((float)d0 + 1.0f);
  }
  if (b == NBINS - 1 && tid == 255) offs[N_NODES] = e1;
  __syncthreads();
  for (int e = e0 + tid; e < e1; e += 256) {
    const unsigned v = benc[e];
    const int p = atomicAdd(&cur[v >> 24], 1);
    brow[p] = (int)(v & 0x00FFFFFFu);
  }
}

// ---------------- gather: one wave per destination node (prescaled bf16) ---
__global__ __launch_bounds__(256) void gather_out(const unsigned short* __restrict__ xwb,
                                                  const float* __restrict__ dinv,
                                                  const int* __restrict__ offs,
                                                  const int* __restrict__ brow,
                                                  const float* __restrict__ bias,
                                                  float* __restrict__ out) {
  const int lane = threadIdx.x & 63;
  const int node = blockIdx.x * (blockDim.x >> 6) + (threadIdx.x >> 6);
  if (node >= N_NODES) return;
  const float di = dinv[node];
  const int c0 = lane * 2;

  auto ld2 = [&](int r) -> float2 {
    const unsigned v = *reinterpret_cast<const unsigned*>(&xwb[(size_t)r * OUT_DIM + c0]);
    float2 f;
    f.x = __builtin_bit_cast(float, v << 16);
    f.y = __builtin_bit_cast(float, v & 0xFFFF0000u);
    return f;
  };

  float2 acc = ld2(node);  // self-loop (prescaled)

  int e = offs[node];
  const int e1 = offs[node + 1];
  for (; e + 8 <= e1; e += 8) {
    const int r0 = brow[e],     r1 = brow[e + 1], r2 = brow[e + 2], r3 = brow[e + 3];
    const int r4 = brow[e + 4], r5 = brow[e + 5], r6 = brow[e + 6], r7 = brow[e + 7];
    const float2 v0 = ld2(r0), v1 = ld2(r1), v2 = ld2(r2), v3 = ld2(r3);
    const float2 v4 = ld2(r4), v5 = ld2(r5), v6 = ld2(r6), v7 = ld2(r7);
    acc.x += ((v0.x + v1.x) + (v2.x + v3.x)) + ((v4.x + v5.x) + (v6.x + v7.x));
    acc.y += ((v0.y + v1.y) + (v2.y + v3.y)) + ((v4.y + v5.y) + (v6.y + v7.y));
  }
  for (; e < e1; ++e) {
    const float2 v = ld2(brow[e]);
    acc.x += v.x;
    acc.y += v.y;
  }

  const float2 bb = *reinterpret_cast<const float2*>(&bias[c0]);
  float2 o;
  o.x = acc.x * di + bb.x;
  o.y = acc.y * di + bb.y;
  *reinterpret_cast<float2*>(&out[(size_t)node * OUT_DIM + c0]) = o;
}

extern "C" void kernel_launch(void* const* d_in, const int* in_sizes, int n_in,
                              void* d_out, int out_size, void* d_ws, size_t ws_size,
                              hipStream_t stream) {
  const float* x    = (const float*)d_in[0];
  const int*   eidx = (const int*)d_in[1];
  const float* W    = (const float*)d_in[2];
  const float* b    = (const float*)d_in[3];
  float* out = (float*)d_out;

  const int* erow = eidx;            // sources
  const int* ecol = eidx + N_EDGES;  // destinations

  char* ws = (char*)d_ws;
  size_t off = 0;
  auto alloc = [&](size_t bytes) -> void* {
    void* p = ws + off;
    off = (off + bytes + 255) & ~(size_t)255;
    return p;
  };
  unsigned short* xwb = (unsigned short*)alloc((size_t)N_NODES * OUT_DIM * sizeof(short)); // 25.6MB
  short* WTb     = (short*)alloc((size_t)OUT_DIM * IN_DIM * sizeof(short));    // 128KB
  float* dinv    = (float*)alloc((size_t)N_NODES * sizeof(float));             // 400KB
  int*   offs    = (int*)alloc((size_t)(N_NODES + 1) * sizeof(int));           // 400KB
  int*   blkhist = (int*)alloc((size_t)NB * NBINS * sizeof(int));              // 1.6MB
  int*   bintot  = (int*)alloc((size_t)NBINS * sizeof(int));
  int*   binbase = (int*)alloc((size_t)(NBINS + 1) * sizeof(int));
  int*   brow    = (int*)alloc((size_t)N_EDGES * sizeof(int));                 // 12.8MB
  unsigned* benc = (unsigned*)alloc((size_t)N_EDGES * sizeof(unsigned));       // 12.8MB

  cast_WT<<<256, 256, 0, stream>>>(W, WTb);

  bin_count<<<NB, 256, 0, stream>>>(ecol, blkhist);
  scan_blkhist<<<NBINS, NB, 0, stream>>>(blkhist, bintot);
  scan_bins<<<1, 512, 0, stream>>>(bintot, binbase);
  bin_scatter<<<NB, 256, 0, stream>>>(erow, ecol, blkhist, binbase, benc);
  bin_build<<<NBINS, 256, 0, stream>>>(benc, binbase, brow, offs, dinv);

  gemm_direct<<<(N_NODES + 63) / 64, 256, 0, stream>>>(x, WTb, dinv, xwb);
  gather_out<<<(N_NODES + 3) / 4, 256, 0, stream>>>(xwb, dinv, offs, brow, b, out);
}

// Round 16
// 292.492 us; speedup vs baseline: 1.2350x; 1.0598x over previous
//
#include <hip/hip_runtime.h>
#include <hip/hip_bf16.h>

using short8  = __attribute__((ext_vector_type(8))) short;
using f32x4   = __attribute__((ext_vector_type(4))) float;
using uint32x4 = __attribute__((ext_vector_type(4))) unsigned;

static constexpr int N_NODES = 100000;
static constexpr int N_EDGES = 3200000;
static constexpr int IN_DIM  = 512;
static constexpr int OUT_DIM = 128;
static constexpr int NBINS   = (N_NODES + 255) / 256;  // 391 bins of 256 nodes
static constexpr int NB      = 1024;                   // binning blocks
static constexpr int CHUNK   = N_EDGES / NB;           // 3125 edges/block (exact)

__device__ __forceinline__ short f2bf(float f) {
  unsigned u = __builtin_bit_cast(unsigned, f);
  u = (u + 0x7FFFu + ((u >> 16) & 1u)) >> 16;  // RNE
  return (short)u;
}

__device__ __forceinline__ void gload16(const void* g, void* l) {
  __builtin_amdgcn_global_load_lds(
      (const __attribute__((address_space(1))) unsigned int*)g,
      (__attribute__((address_space(3))) unsigned int*)l, 16, 0, 0);
}

// ---------------- W [512][128] f32 -> WT [128][512] bf16 (col-major W) ----
__global__ __launch_bounds__(256) void cast_WT(const float* __restrict__ W,
                                               short* __restrict__ WT) {
  const int idx = blockIdx.x * 256 + threadIdx.x;  // 65536 total
  const int c = idx >> 9, k = idx & 511;
  WT[(size_t)c * 512 + k] = f2bf(W[(size_t)k * 128 + c]);
}

// ------------- m97-style LDS GEMM: xwb = (x@W)*dinv, bf16 out -------------
// Block 128x128, 4 waves (2x2), wave 64x64. BK=32, 16 steps, dbuf LDS.
// A f32 staged via global_load_lds with source-side XOR swizzle u^(row&7);
// B bf16 staged likewise with u^(col&3). Single barrier per step.
__global__ __launch_bounds__(256) void gemm_lds(const float* __restrict__ x,
                                                const short* __restrict__ WT,
                                                const float* __restrict__ dinv,
                                                unsigned short* __restrict__ xwb) {
  __shared__ float          Abuf[2][128 * 32];  // 2 x 16KB
  __shared__ unsigned short Bbuf[2][128 * 32];  // 2 x 8KB
  const int tid = threadIdx.x;
  const int w   = tid >> 6;
  const int l   = tid & 63;
  const int wr  = w >> 1, wc = w & 1;
  const int lr  = l & 15;
  const int lk  = l >> 4;
  const int row0 = blockIdx.x * 128;
  const char* xb  = reinterpret_cast<const char*>(x);
  const char* wtb = reinterpret_cast<const char*>(WT);
  const int wbase = (tid & ~63) * 16;  // wave-uniform LDS chunk base (bytes)

  auto stage = [&](int kb, int buf) {
    // A: 128 rows x 32 f32 (8x16B units/row), src swizzled by u^(row&7)
#pragma unroll
    for (int t = 0; t < 4; ++t) {
      const int f = t * 256 + tid;  // unit index 0..1023
      const int r = f >> 3;
      const int u = f & 7;
      const int grow = min(row0 + r, N_NODES - 1);
      const char* src = xb + (size_t)grow * 2048 + kb * 128 + ((u ^ (r & 7)) << 4);
      gload16(src, (char*)Abuf[buf] + t * 4096 + wbase);
    }
    // B: 128 cols x 32 bf16 (4x16B units/col), src swizzled by u^(col&3)
#pragma unroll
    for (int t = 0; t < 2; ++t) {
      const int f = t * 256 + tid;  // unit index 0..511
      const int c = f >> 2;
      const int u = f & 3;
      const char* src = wtb + (size_t)c * 1024 + kb * 64 + ((u ^ (c & 3)) << 4);
      gload16(src, (char*)Bbuf[buf] + t * 4096 + wbase);
    }
  };

  auto cvt2 = [](float lo, float hi) -> unsigned {
    __hip_bfloat162 h = __float22bfloat162_rn(make_float2(lo, hi));
    unsigned r;
    __builtin_memcpy(&r, &h, 4);
    return r;
  };

  f32x4 acc[4][4] = {};

  auto compute = [&](int buf) {
    const char* Ab = (const char*)Abuf[buf];
    const char* Bb = (const char*)Bbuf[buf];
    short8 a[4], b[4];
#pragma unroll
    for (int rf = 0; rf < 4; ++rf) {
      const int rl = wr * 64 + rf * 16 + lr;
      const char* base = Ab + rl * 128;
      const f32x4 r0 = *(const f32x4*)(base + (((2 * lk)     ^ (rl & 7)) << 4));
      const f32x4 r1 = *(const f32x4*)(base + (((2 * lk + 1) ^ (rl & 7)) << 4));
      uint32x4 ua;
      ua[0] = cvt2(r0[0], r0[1]);
      ua[1] = cvt2(r0[2], r0[3]);
      ua[2] = cvt2(r1[0], r1[1]);
      ua[3] = cvt2(r1[2], r1[3]);
      a[rf] = __builtin_bit_cast(short8, ua);
    }
#pragma unroll
    for (int cf = 0; cf < 4; ++cf) {
      const int cl = wc * 64 + cf * 16 + lr;
      b[cf] = *(const short8*)(Bb + cl * 64 + ((lk ^ (cl & 3)) << 4));
    }
#pragma unroll
    for (int rf = 0; rf < 4; ++rf)
#pragma unroll
      for (int cf = 0; cf < 4; ++cf)
        acc[rf][cf] = __builtin_amdgcn_mfma_f32_16x16x32_bf16(a[rf], b[cf], acc[rf][cf], 0, 0, 0);
  };

  stage(0, 0);
  __syncthreads();
  for (int kb = 0; kb < 16; ++kb) {
    if (kb < 15) stage(kb + 1, (kb + 1) & 1);
    compute(kb & 1);
    __syncthreads();
  }

  // C/D: col = wc*64 + cf*16 + lr, row = row0 + wr*64 + rf*16 + lk*4 + j
#pragma unroll
  for (int rf = 0; rf < 4; ++rf) {
#pragma unroll
    for (int j = 0; j < 4; ++j) {
      const int row = row0 + wr * 64 + rf * 16 + lk * 4 + j;
      if (row < N_NODES) {
        const float sc = dinv[row];  // prescale: xwb = xw * dinv[row]
        unsigned short* o = &xwb[(size_t)row * OUT_DIM + wc * 64 + lr];
#pragma unroll
        for (int cf = 0; cf < 4; ++cf)
          o[cf * 16] = (unsigned short)f2bf(acc[rf][cf][j] * sc);
      }
    }
  }
}

// ========== atomic-free edge grouping: 2-level binning, LDS-only atomics ====

// A1: per-block LDS histogram of bin = col>>8
__global__ __launch_bounds__(256) void bin_count(const int* __restrict__ ecol,
                                                 int* __restrict__ blkhist) {
  __shared__ int hist[NBINS];
  const int blk = blockIdx.x, tid = threadIdx.x;
  for (int i = tid; i < NBINS; i += 256) hist[i] = 0;
  __syncthreads();
  const int e0 = blk * CHUNK, e1 = e0 + CHUNK;
  for (int e = e0 + tid; e < e1; e += 256) atomicAdd(&hist[ecol[e] >> 8], 1);
  __syncthreads();
  for (int i = tid; i < NBINS; i += 256) blkhist[(size_t)blk * NBINS + i] = hist[i];
}

// A2a: per-bin exclusive scan over the NB block partials (in place)
__global__ __launch_bounds__(1024) void scan_blkhist(int* __restrict__ blkhist,
                                                     int* __restrict__ bintot) {
  __shared__ int sh[NB];
  const int bin = blockIdx.x, t = threadIdx.x;
  const int v = blkhist[(size_t)t * NBINS + bin];
  sh[t] = v;
  __syncthreads();
  for (int d = 1; d < NB; d <<= 1) {
    const int tv = (t >= d) ? sh[t - d] : 0;
    __syncthreads();
    sh[t] += tv;
    __syncthreads();
  }
  blkhist[(size_t)t * NBINS + bin] = sh[t] - v;  // exclusive prefix over blocks
  if (t == NB - 1) bintot[bin] = sh[t];
}

// A2b: exclusive scan over bin totals
__global__ __launch_bounds__(512) void scan_bins(const int* __restrict__ bintot,
                                                 int* __restrict__ binbase) {
  __shared__ int sh[512];
  const int t = threadIdx.x;
  const int v = (t < NBINS) ? bintot[t] : 0;
  sh[t] = v;
  __syncthreads();
  for (int d = 1; d < 512; d <<= 1) {
    const int tv = (t >= d) ? sh[t - d] : 0;
    __syncthreads();
    sh[t] += tv;
    __syncthreads();
  }
  if (t < NBINS) binbase[t] = sh[t] - v;
  if (t == NBINS - 1) binbase[NBINS] = sh[t];
}

// A3: scatter packed (local_col<<24 | row) into bin-segmented benc
__global__ __launch_bounds__(256) void bin_scatter(const int* __restrict__ erow,
                                                   const int* __restrict__ ecol,
                                                   const int* __restrict__ blkhist,
                                                   const int* __restrict__ binbase,
                                                   unsigned* __restrict__ benc) {
  __shared__ int cur[NBINS];
  const int blk = blockIdx.x, tid = threadIdx.x;
  for (int i = tid; i < NBINS; i += 256)
    cur[i] = binbase[i] + blkhist[(size_t)blk * NBINS + i];
  __syncthreads();
  const int e0 = blk * CHUNK, e1 = e0 + CHUNK;
  for (int e = e0 + tid; e < e1; e += 256) {
    const int c = ecol[e];
    const unsigned enc = (unsigned)erow[e] | ((unsigned)(c & 255) << 24);
    const int p = atomicAdd(&cur[c >> 8], 1);
    benc[p] = enc;
  }
}

// B: per-bin CSR build — offs, dinv, brow (one block per 256-node bin)
__global__ __launch_bounds__(256) void bin_build(const unsigned* __restrict__ benc,
                                                 const int* __restrict__ binbase,
                                                 int* __restrict__ brow,
                                                 int* __restrict__ offs,
                                                 float* __restrict__ dinv) {
  __shared__ int hist[256];
  __shared__ int sh[256];
  __shared__ int cur[256];
  const int b = blockIdx.x, tid = threadIdx.x;
  const int e0 = binbase[b], e1 = binbase[b + 1];
  hist[tid] = 0;
  __syncthreads();
  for (int e = e0 + tid; e < e1; e += 256) atomicAdd(&hist[benc[e] >> 24], 1);
  __syncthreads();
  const int d0 = hist[tid];
  sh[tid] = d0;
  __syncthreads();
  for (int d = 1; d < 256; d <<= 1) {
    const int tv = (tid >= d) ? sh[tid - d] : 0;
    __syncthreads();
    sh[tid] += tv;
    __syncthreads();
  }
  const int myoff = e0 + sh[tid] - d0;  // global CSR offset for node (b<<8)+tid
  cur[tid] = myoff;
  const int node = (b << 8) + tid;
  if (node < N_NODES) {
    offs[node] = myoff;
    dinv[node] = rsqrtf((float)d0 + 1.0f);
  }
  if (b == NBINS - 1 && tid == 255) offs[N_NODES] = e1;
  __syncthreads();
  for (int e = e0 + tid; e < e1; e += 256) {
    const unsigned v = benc[e];
    const int p = atomicAdd(&cur[v >> 24], 1);
    brow[p] = (int)(v & 0x00FFFFFFu);
  }
}

// ---------------- gather: one wave per destination node (prescaled bf16) ---
__global__ __launch_bounds__(256) void gather_out(const unsigned short* __restrict__ xwb,
                                                  const float* __restrict__ dinv,
                                                  const int* __restrict__ offs,
                                                  const int* __restrict__ brow,
                                                  const float* __restrict__ bias,
                                                  float* __restrict__ out) {
  const int lane = threadIdx.x & 63;
  const int node = blockIdx.x * (blockDim.x >> 6) + (threadIdx.x >> 6);
  if (node >= N_NODES) return;
  const float di = dinv[node];
  const int c0 = lane * 2;

  auto ld2 = [&](int r) -> float2 {
    const unsigned v = *reinterpret_cast<const unsigned*>(&xwb[(size_t)r * OUT_DIM + c0]);
    float2 f;
    f.x = __builtin_bit_cast(float, v << 16);
    f.y = __builtin_bit_cast(float, v & 0xFFFF0000u);
    return f;
  };

  float2 acc = ld2(node);  // self-loop (prescaled)

  int e = offs[node];
  const int e1 = offs[node + 1];
  for (; e + 8 <= e1; e += 8) {
    const int r0 = brow[e],     r1 = brow[e + 1], r2 = brow[e + 2], r3 = brow[e + 3];
    const int r4 = brow[e + 4], r5 = brow[e + 5], r6 = brow[e + 6], r7 = brow[e + 7];
    const float2 v0 = ld2(r0), v1 = ld2(r1), v2 = ld2(r2), v3 = ld2(r3);
    const float2 v4 = ld2(r4), v5 = ld2(r5), v6 = ld2(r6), v7 = ld2(r7);
    acc.x += ((v0.x + v1.x) + (v2.x + v3.x)) + ((v4.x + v5.x) + (v6.x + v7.x));
    acc.y += ((v0.y + v1.y) + (v2.y + v3.y)) + ((v4.y + v5.y) + (v6.y + v7.y));
  }
  for (; e < e1; ++e) {
    const float2 v = ld2(brow[e]);
    acc.x += v.x;
    acc.y += v.y;
  }

  const float2 bb = *reinterpret_cast<const float2*>(&bias[c0]);
  float2 o;
  o.x = acc.x * di + bb.x;
  o.y = acc.y * di + bb.y;
  *reinterpret_cast<float2*>(&out[(size_t)node * OUT_DIM + c0]) = o;
}

extern "C" void kernel_launch(void* const* d_in, const int* in_sizes, int n_in,
                              void* d_out, int out_size, void* d_ws, size_t ws_size,
                              hipStream_t stream) {
  const float* x    = (const float*)d_in[0];
  const int*   eidx = (const int*)d_in[1];
  const float* W    = (const float*)d_in[2];
  const float* b    = (const float*)d_in[3];
  float* out = (float*)d_out;

  const int* erow = eidx;            // sources
  const int* ecol = eidx + N_EDGES;  // destinations

  char* ws = (char*)d_ws;
  size_t off = 0;
  auto alloc = [&](size_t bytes) -> void* {
    void* p = ws + off;
    off = (off + bytes + 255) & ~(size_t)255;
    return p;
  };
  unsigned short* xwb = (unsigned short*)alloc((size_t)N_NODES * OUT_DIM * sizeof(short)); // 25.6MB
  short* WT      = (short*)alloc((size_t)OUT_DIM * IN_DIM * sizeof(short));    // 128KB
  float* dinv    = (float*)alloc((size_t)N_NODES * sizeof(float));             // 400KB
  int*   offs    = (int*)alloc((size_t)(N_NODES + 1) * sizeof(int));           // 400KB
  int*   blkhist = (int*)alloc((size_t)NB * NBINS * sizeof(int));              // 1.6MB
  int*   bintot  = (int*)alloc((size_t)NBINS * sizeof(int));
  int*   binbase = (int*)alloc((size_t)(NBINS + 1) * sizeof(int));
  int*   brow    = (int*)alloc((size_t)N_EDGES * sizeof(int));                 // 12.8MB
  unsigned* benc = (unsigned*)alloc((size_t)N_EDGES * sizeof(unsigned));       // 12.8MB

  cast_WT<<<256, 256, 0, stream>>>(W, WT);

  bin_count<<<NB, 256, 0, stream>>>(ecol, blkhist);
  scan_blkhist<<<NBINS, NB, 0, stream>>>(blkhist, bintot);
  scan_bins<<<1, 512, 0, stream>>>(bintot, binbase);
  bin_scatter<<<NB, 256, 0, stream>>>(erow, ecol, blkhist, binbase, benc);
  bin_build<<<NBINS, 256, 0, stream>>>(benc, binbase, brow, offs, dinv);

  gemm_lds<<<(N_NODES + 127) / 128, 256, 0, stream>>>(x, WT, dinv, xwb);
  gather_out<<<(N_NODES + 3) / 4, 256, 0, stream>>>(xwb, dinv, offs, brow, b, out);
}

// Round 17
// 289.234 us; speedup vs baseline: 1.2489x; 1.0113x over previous
//
#include <hip/hip_runtime.h>
#include <hip/hip_bf16.h>

using short8  = __attribute__((ext_vector_type(8))) short;
using f32x4   = __attribute__((ext_vector_type(4))) float;
using uint32x4 = __attribute__((ext_vector_type(4))) unsigned;

static constexpr int N_NODES = 100000;
static constexpr int N_EDGES = 3200000;
static constexpr int IN_DIM  = 512;
static constexpr int OUT_DIM = 128;
static constexpr int NBINS   = (N_NODES + 255) / 256;  // 391 bins of 256 nodes
static constexpr int NB      = 1024;                   // binning blocks
static constexpr int CHUNK   = N_EDGES / NB;           // 3125 edges/block (exact)

__device__ __forceinline__ short f2bf(float f) {
  unsigned u = __builtin_bit_cast(unsigned, f);
  u = (u + 0x7FFFu + ((u >> 16) & 1u)) >> 16;  // RNE
  return (short)u;
}

__device__ __forceinline__ void gload16(const void* g, void* l) {
  __builtin_amdgcn_global_load_lds(
      (const __attribute__((address_space(1))) unsigned int*)g,
      (__attribute__((address_space(3))) unsigned int*)l, 16, 0, 0);
}

// ---------------- W [512][128] f32 -> WT [128][512] bf16 (col-major W) ----
__global__ __launch_bounds__(256) void cast_WT(const float* __restrict__ W,
                                               short* __restrict__ WT) {
  const int idx = blockIdx.x * 256 + threadIdx.x;  // 65536 total
  const int c = idx >> 9, k = idx & 511;
  WT[(size_t)c * 512 + k] = f2bf(W[(size_t)k * 128 + c]);
}

// ------------- m97-style LDS GEMM: xwb = (x@W)*dinv, bf16 out -------------
__global__ __launch_bounds__(256) void gemm_lds(const float* __restrict__ x,
                                                const short* __restrict__ WT,
                                                const float* __restrict__ dinv,
                                                unsigned short* __restrict__ xwb) {
  __shared__ float          Abuf[2][128 * 32];  // 2 x 16KB
  __shared__ unsigned short Bbuf[2][128 * 32];  // 2 x 8KB
  const int tid = threadIdx.x;
  const int w   = tid >> 6;
  const int l   = tid & 63;
  const int wr  = w >> 1, wc = w & 1;
  const int lr  = l & 15;
  const int lk  = l >> 4;
  const int row0 = blockIdx.x * 128;
  const char* xb  = reinterpret_cast<const char*>(x);
  const char* wtb = reinterpret_cast<const char*>(WT);
  const int wbase = (tid & ~63) * 16;  // wave-uniform LDS chunk base (bytes)

  auto stage = [&](int kb, int buf) {
#pragma unroll
    for (int t = 0; t < 4; ++t) {
      const int f = t * 256 + tid;  // unit index 0..1023
      const int r = f >> 3;
      const int u = f & 7;
      const int grow = min(row0 + r, N_NODES - 1);
      const char* src = xb + (size_t)grow * 2048 + kb * 128 + ((u ^ (r & 7)) << 4);
      gload16(src, (char*)Abuf[buf] + t * 4096 + wbase);
    }
#pragma unroll
    for (int t = 0; t < 2; ++t) {
      const int f = t * 256 + tid;  // unit index 0..511
      const int c = f >> 2;
      const int u = f & 3;
      const char* src = wtb + (size_t)c * 1024 + kb * 64 + ((u ^ (c & 3)) << 4);
      gload16(src, (char*)Bbuf[buf] + t * 4096 + wbase);
    }
  };

  auto cvt2 = [](float lo, float hi) -> unsigned {
    __hip_bfloat162 h = __float22bfloat162_rn(make_float2(lo, hi));
    unsigned r;
    __builtin_memcpy(&r, &h, 4);
    return r;
  };

  f32x4 acc[4][4] = {};

  auto compute = [&](int buf) {
    const char* Ab = (const char*)Abuf[buf];
    const char* Bb = (const char*)Bbuf[buf];
    short8 a[4], b[4];
#pragma unroll
    for (int rf = 0; rf < 4; ++rf) {
      const int rl = wr * 64 + rf * 16 + lr;
      const char* base = Ab + rl * 128;
      const f32x4 r0 = *(const f32x4*)(base + (((2 * lk)     ^ (rl & 7)) << 4));
      const f32x4 r1 = *(const f32x4*)(base + (((2 * lk + 1) ^ (rl & 7)) << 4));
      uint32x4 ua;
      ua[0] = cvt2(r0[0], r0[1]);
      ua[1] = cvt2(r0[2], r0[3]);
      ua[2] = cvt2(r1[0], r1[1]);
      ua[3] = cvt2(r1[2], r1[3]);
      a[rf] = __builtin_bit_cast(short8, ua);
    }
#pragma unroll
    for (int cf = 0; cf < 4; ++cf) {
      const int cl = wc * 64 + cf * 16 + lr;
      b[cf] = *(const short8*)(Bb + cl * 64 + ((lk ^ (cl & 3)) << 4));
    }
#pragma unroll
    for (int rf = 0; rf < 4; ++rf)
#pragma unroll
      for (int cf = 0; cf < 4; ++cf)
        acc[rf][cf] = __builtin_amdgcn_mfma_f32_16x16x32_bf16(a[rf], b[cf], acc[rf][cf], 0, 0, 0);
  };

  stage(0, 0);
  __syncthreads();
  for (int kb = 0; kb < 16; ++kb) {
    if (kb < 15) stage(kb + 1, (kb + 1) & 1);
    compute(kb & 1);
    __syncthreads();
  }

#pragma unroll
  for (int rf = 0; rf < 4; ++rf) {
#pragma unroll
    for (int j = 0; j < 4; ++j) {
      const int row = row0 + wr * 64 + rf * 16 + lk * 4 + j;
      if (row < N_NODES) {
        const float sc = dinv[row];  // prescale: xwb = xw * dinv[row]
        unsigned short* o = &xwb[(size_t)row * OUT_DIM + wc * 64 + lr];
#pragma unroll
        for (int cf = 0; cf < 4; ++cf)
          o[cf * 16] = (unsigned short)f2bf(acc[rf][cf][j] * sc);
      }
    }
  }
}

// ========== atomic-free edge grouping: 2-level binning, LDS-only atomics ====

__global__ __launch_bounds__(256) void bin_count(const int* __restrict__ ecol,
                                                 int* __restrict__ blkhist) {
  __shared__ int hist[NBINS];
  const int blk = blockIdx.x, tid = threadIdx.x;
  for (int i = tid; i < NBINS; i += 256) hist[i] = 0;
  __syncthreads();
  const int e0 = blk * CHUNK, e1 = e0 + CHUNK;
  for (int e = e0 + tid; e < e1; e += 256) atomicAdd(&hist[ecol[e] >> 8], 1);
  __syncthreads();
  for (int i = tid; i < NBINS; i += 256) blkhist[(size_t)blk * NBINS + i] = hist[i];
}

__global__ __launch_bounds__(1024) void scan_blkhist(int* __restrict__ blkhist,
                                                     int* __restrict__ bintot) {
  __shared__ int sh[NB];
  const int bin = blockIdx.x, t = threadIdx.x;
  const int v = blkhist[(size_t)t * NBINS + bin];
  sh[t] = v;
  __syncthreads();
  for (int d = 1; d < NB; d <<= 1) {
    const int tv = (t >= d) ? sh[t - d] : 0;
    __syncthreads();
    sh[t] += tv;
    __syncthreads();
  }
  blkhist[(size_t)t * NBINS + bin] = sh[t] - v;  // exclusive prefix over blocks
  if (t == NB - 1) bintot[bin] = sh[t];
}

__global__ __launch_bounds__(512) void scan_bins(const int* __restrict__ bintot,
                                                 int* __restrict__ binbase) {
  __shared__ int sh[512];
  const int t = threadIdx.x;
  const int v = (t < NBINS) ? bintot[t] : 0;
  sh[t] = v;
  __syncthreads();
  for (int d = 1; d < 512; d <<= 1) {
    const int tv = (t >= d) ? sh[t - d] : 0;
    __syncthreads();
    sh[t] += tv;
    __syncthreads();
  }
  if (t < NBINS) binbase[t] = sh[t] - v;
  if (t == NBINS - 1) binbase[NBINS] = sh[t];
}

__global__ __launch_bounds__(256) void bin_scatter(const int* __restrict__ erow,
                                                   const int* __restrict__ ecol,
                                                   const int* __restrict__ blkhist,
                                                   const int* __restrict__ binbase,
                                                   unsigned* __restrict__ benc) {
  __shared__ int cur[NBINS];
  const int blk = blockIdx.x, tid = threadIdx.x;
  for (int i = tid; i < NBINS; i += 256)
    cur[i] = binbase[i] + blkhist[(size_t)blk * NBINS + i];
  __syncthreads();
  const int e0 = blk * CHUNK, e1 = e0 + CHUNK;
  for (int e = e0 + tid; e < e1; e += 256) {
    const int c = ecol[e];
    const unsigned enc = (unsigned)erow[e] | ((unsigned)(c & 255) << 24);
    const int p = atomicAdd(&cur[c >> 8], 1);
    benc[p] = enc;
  }
}

__global__ __launch_bounds__(256) void bin_build(const unsigned* __restrict__ benc,
                                                 const int* __restrict__ binbase,
                                                 int* __restrict__ brow,
                                                 int* __restrict__ offs,
                                                 float* __restrict__ dinv) {
  __shared__ int hist[256];
  __shared__ int sh[256];
  __shared__ int cur[256];
  const int b = blockIdx.x, tid = threadIdx.x;
  const int e0 = binbase[b], e1 = binbase[b + 1];
  hist[tid] = 0;
  __syncthreads();
  for (int e = e0 + tid; e < e1; e += 256) atomicAdd(&hist[benc[e] >> 24], 1);
  __syncthreads();
  const int d0 = hist[tid];
  sh[tid] = d0;
  __syncthreads();
  for (int d = 1; d < 256; d <<= 1) {
    const int tv = (tid >= d) ? sh[tid - d] : 0;
    __syncthreads();
    sh[tid] += tv;
    __syncthreads();
  }
  const int myoff = e0 + sh[tid] - d0;  // global CSR offset for node (b<<8)+tid
  cur[tid] = myoff;
  const int node = (b << 8) + tid;
  if (node < N_NODES) {
    offs[node] = myoff;
    dinv[node] = rsqrtf((float)d0 + 1.0f);
  }
  if (b == NBINS - 1 && tid == 255) offs[N_NODES] = e1;
  __syncthreads();
  for (int e = e0 + tid; e < e1; e += 256) {
    const unsigned v = benc[e];
    const int p = atomicAdd(&cur[v >> 24], 1);
    brow[p] = (int)(v & 0x00FFFFFFu);
  }
}

// ------- gather: one wave per node, 16-deep in-flight gathers -------------
__global__ __launch_bounds__(256) void gather_out(const unsigned short* __restrict__ xwb,
                                                  const float* __restrict__ dinv,
                                                  const int* __restrict__ offs,
                                                  const int* __restrict__ brow,
                                                  const float* __restrict__ bias,
                                                  float* __restrict__ out) {
  const int lane = threadIdx.x & 63;
  const int node = blockIdx.x * (blockDim.x >> 6) + (threadIdx.x >> 6);
  if (node >= N_NODES) return;
  const float di = dinv[node];
  const int c0 = lane * 2;

  auto ld2 = [&](int r) -> float2 {
    const unsigned v = *reinterpret_cast<const unsigned*>(&xwb[(size_t)r * OUT_DIM + c0]);
    float2 f;
    f.x = __builtin_bit_cast(float, v << 16);
    f.y = __builtin_bit_cast(float, v & 0xFFFF0000u);
    return f;
  };

  float2 acc = ld2(node);  // self-loop (prescaled)
  float2 acc2 = make_float2(0.f, 0.f);

  int e = offs[node];
  const int e1 = offs[node + 1];
  for (; e + 16 <= e1; e += 16) {
    int r[16];
#pragma unroll
    for (int i = 0; i < 16; ++i) r[i] = brow[e + i];
    float2 v[16];
#pragma unroll
    for (int i = 0; i < 16; ++i) v[i] = ld2(r[i]);
#pragma unroll
    for (int i = 0; i < 16; i += 2) {
      acc.x  += v[i].x     + v[i + 1].x;
      acc.y  += v[i].y     + v[i + 1].y;
    }
  }
  for (; e + 4 <= e1; e += 4) {
    const int r0 = brow[e], r1 = brow[e + 1], r2 = brow[e + 2], r3 = brow[e + 3];
    const float2 v0 = ld2(r0), v1 = ld2(r1), v2 = ld2(r2), v3 = ld2(r3);
    acc2.x += (v0.x + v1.x) + (v2.x + v3.x);
    acc2.y += (v0.y + v1.y) + (v2.y + v3.y);
  }
  for (; e < e1; ++e) {
    const float2 v = ld2(brow[e]);
    acc2.x += v.x;
    acc2.y += v.y;
  }
  acc.x += acc2.x;
  acc.y += acc2.y;

  const float2 bb = *reinterpret_cast<const float2*>(&bias[c0]);
  float2 o;
  o.x = acc.x * di + bb.x;
  o.y = acc.y * di + bb.y;
  *reinterpret_cast<float2*>(&out[(size_t)node * OUT_DIM + c0]) = o;
}

extern "C" void kernel_launch(void* const* d_in, const int* in_sizes, int n_in,
                              void* d_out, int out_size, void* d_ws, size_t ws_size,
                              hipStream_t stream) {
  const float* x    = (const float*)d_in[0];
  const int*   eidx = (const int*)d_in[1];
  const float* W    = (const float*)d_in[2];
  const float* b    = (const float*)d_in[3];
  float* out = (float*)d_out;

  const int* erow = eidx;            // sources
  const int* ecol = eidx + N_EDGES;  // destinations

  char* ws = (char*)d_ws;
  size_t off = 0;
  auto alloc = [&](size_t bytes) -> void* {
    void* p = ws + off;
    off = (off + bytes + 255) & ~(size_t)255;
    return p;
  };
  unsigned short* xwb = (unsigned short*)alloc((size_t)N_NODES * OUT_DIM * sizeof(short)); // 25.6MB
  short* WT      = (short*)alloc((size_t)OUT_DIM * IN_DIM * sizeof(short));    // 128KB
  float* dinv    = (float*)alloc((size_t)N_NODES * sizeof(float));             // 400KB
  int*   offs    = (int*)alloc((size_t)(N_NODES + 1) * sizeof(int));           // 400KB
  int*   blkhist = (int*)alloc((size_t)NB * NBINS * sizeof(int));              // 1.6MB
  int*   bintot  = (int*)alloc((size_t)NBINS * sizeof(int));
  int*   binbase = (int*)alloc((size_t)(NBINS + 1) * sizeof(int));
  int*   brow    = (int*)alloc((size_t)N_EDGES * sizeof(int));                 // 12.8MB
  unsigned* benc = (unsigned*)alloc((size_t)N_EDGES * sizeof(unsigned));       // 12.8MB

  cast_WT<<<256, 256, 0, stream>>>(W, WT);

  bin_count<<<NB, 256, 0, stream>>>(ecol, blkhist);
  scan_blkhist<<<NBINS, NB, 0, stream>>>(blkhist, bintot);
  scan_bins<<<1, 512, 0, stream>>>(bintot, binbase);
  bin_scatter<<<NB, 256, 0, stream>>>(erow, ecol, blkhist, binbase, benc);
  bin_build<<<NBINS, 256, 0, stream>>>(benc, binbase, brow, offs, dinv);

  gemm_lds<<<(N_NODES + 127) / 128, 256, 0, stream>>>(x, WT, dinv, xwb);
  gather_out<<<(N_NODES + 3) / 4, 256, 0, stream>>>(xwb, dinv, offs, brow, b, out);
}

// Round 18
// 287.785 us; speedup vs baseline: 1.2552x; 1.0050x over previous
//
#include <hip/hip_runtime.h>
#include <hip/hip_bf16.h>

using short8  = __attribute__((ext_vector_type(8))) short;
using f32x4   = __attribute__((ext_vector_type(4))) float;
using uint32x4 = __attribute__((ext_vector_type(4))) unsigned;

static constexpr int N_NODES = 100000;
static constexpr int N_EDGES = 3200000;
static constexpr int IN_DIM  = 512;
static constexpr int OUT_DIM = 128;
static constexpr int NBINS   = (N_NODES + 255) / 256;  // 391 bins of 256 nodes
static constexpr int NB      = 1024;                   // binning blocks
static constexpr int CHUNK   = N_EDGES / NB;           // 3125 edges/block (exact)
static constexpr int RSH     = 13;                     // source-range shift
static constexpr int NRANGE  = (N_NODES + (1 << RSH) - 1) >> RSH;  // 13

__device__ __forceinline__ short f2bf(float f) {
  unsigned u = __builtin_bit_cast(unsigned, f);
  u = (u + 0x7FFFu + ((u >> 16) & 1u)) >> 16;  // RNE
  return (short)u;
}

__device__ __forceinline__ void gload16(const void* g, void* l) {
  __builtin_amdgcn_global_load_lds(
      (const __attribute__((address_space(1))) unsigned int*)g,
      (__attribute__((address_space(3))) unsigned int*)l, 16, 0, 0);
}

// ---------------- W [512][128] f32 -> WT [128][512] bf16 (col-major W) ----
__global__ __launch_bounds__(256) void cast_WT(const float* __restrict__ W,
                                               short* __restrict__ WT) {
  const int idx = blockIdx.x * 256 + threadIdx.x;  // 65536 total
  const int c = idx >> 9, k = idx & 511;
  WT[(size_t)c * 512 + k] = f2bf(W[(size_t)k * 128 + c]);
}

// ------------- m97-style LDS GEMM: xwb = (x@W)*dinv, bf16 out -------------
__global__ __launch_bounds__(256) void gemm_lds(const float* __restrict__ x,
                                                const short* __restrict__ WT,
                                                const float* __restrict__ dinv,
                                                unsigned short* __restrict__ xwb) {
  __shared__ float          Abuf[2][128 * 32];  // 2 x 16KB
  __shared__ unsigned short Bbuf[2][128 * 32];  // 2 x 8KB
  const int tid = threadIdx.x;
  const int w   = tid >> 6;
  const int l   = tid & 63;
  const int wr  = w >> 1, wc = w & 1;
  const int lr  = l & 15;
  const int lk  = l >> 4;
  const int row0 = blockIdx.x * 128;
  const char* xb  = reinterpret_cast<const char*>(x);
  const char* wtb = reinterpret_cast<const char*>(WT);
  const int wbase = (tid & ~63) * 16;  // wave-uniform LDS chunk base (bytes)

  auto stage = [&](int kb, int buf) {
#pragma unroll
    for (int t = 0; t < 4; ++t) {
      const int f = t * 256 + tid;  // unit index 0..1023
      const int r = f >> 3;
      const int u = f & 7;
      const int grow = min(row0 + r, N_NODES - 1);
      const char* src = xb + (size_t)grow * 2048 + kb * 128 + ((u ^ (r & 7)) << 4);
      gload16(src, (char*)Abuf[buf] + t * 4096 + wbase);
    }
#pragma unroll
    for (int t = 0; t < 2; ++t) {
      const int f = t * 256 + tid;  // unit index 0..511
      const int c = f >> 2;
      const int u = f & 3;
      const char* src = wtb + (size_t)c * 1024 + kb * 64 + ((u ^ (c & 3)) << 4);
      gload16(src, (char*)Bbuf[buf] + t * 4096 + wbase);
    }
  };

  auto cvt2 = [](float lo, float hi) -> unsigned {
    __hip_bfloat162 h = __float22bfloat162_rn(make_float2(lo, hi));
    unsigned r;
    __builtin_memcpy(&r, &h, 4);
    return r;
  };

  f32x4 acc[4][4] = {};

  auto compute = [&](int buf) {
    const char* Ab = (const char*)Abuf[buf];
    const char* Bb = (const char*)Bbuf[buf];
    short8 a[4], b[4];
#pragma unroll
    for (int rf = 0; rf < 4; ++rf) {
      const int rl = wr * 64 + rf * 16 + lr;
      const char* base = Ab + rl * 128;
      const f32x4 r0 = *(const f32x4*)(base + (((2 * lk)     ^ (rl & 7)) << 4));
      const f32x4 r1 = *(const f32x4*)(base + (((2 * lk + 1) ^ (rl & 7)) << 4));
      uint32x4 ua;
      ua[0] = cvt2(r0[0], r0[1]);
      ua[1] = cvt2(r0[2], r0[3]);
      ua[2] = cvt2(r1[0], r1[1]);
      ua[3] = cvt2(r1[2], r1[3]);
      a[rf] = __builtin_bit_cast(short8, ua);
    }
#pragma unroll
    for (int cf = 0; cf < 4; ++cf) {
      const int cl = wc * 64 + cf * 16 + lr;
      b[cf] = *(const short8*)(Bb + cl * 64 + ((lk ^ (cl & 3)) << 4));
    }
#pragma unroll
    for (int rf = 0; rf < 4; ++rf)
#pragma unroll
      for (int cf = 0; cf < 4; ++cf)
        acc[rf][cf] = __builtin_amdgcn_mfma_f32_16x16x32_bf16(a[rf], b[cf], acc[rf][cf], 0, 0, 0);
  };

  stage(0, 0);
  __syncthreads();
  for (int kb = 0; kb < 16; ++kb) {
    if (kb < 15) stage(kb + 1, (kb + 1) & 1);
    compute(kb & 1);
    __syncthreads();
  }

#pragma unroll
  for (int rf = 0; rf < 4; ++rf) {
#pragma unroll
    for (int j = 0; j < 4; ++j) {
      const int row = row0 + wr * 64 + rf * 16 + lk * 4 + j;
      if (row < N_NODES) {
        const float sc = dinv[row];  // prescale: xwb = xw * dinv[row]
        unsigned short* o = &xwb[(size_t)row * OUT_DIM + wc * 64 + lr];
#pragma unroll
        for (int cf = 0; cf < 4; ++cf)
          o[cf * 16] = (unsigned short)f2bf(acc[rf][cf][j] * sc);
      }
    }
  }
}

// ========== atomic-free edge grouping: 2-level binning, LDS-only atomics ====

__global__ __launch_bounds__(256) void bin_count(const int* __restrict__ ecol,
                                                 int* __restrict__ blkhist) {
  __shared__ int hist[NBINS];
  const int blk = blockIdx.x, tid = threadIdx.x;
  for (int i = tid; i < NBINS; i += 256) hist[i] = 0;
  __syncthreads();
  const int e0 = blk * CHUNK, e1 = e0 + CHUNK;
  for (int e = e0 + tid; e < e1; e += 256) atomicAdd(&hist[ecol[e] >> 8], 1);
  __syncthreads();
  for (int i = tid; i < NBINS; i += 256) blkhist[(size_t)blk * NBINS + i] = hist[i];
}

__global__ __launch_bounds__(1024) void scan_blkhist(int* __restrict__ blkhist,
                                                     int* __restrict__ bintot) {
  __shared__ int sh[NB];
  const int bin = blockIdx.x, t = threadIdx.x;
  const int v = blkhist[(size_t)t * NBINS + bin];
  sh[t] = v;
  __syncthreads();
  for (int d = 1; d < NB; d <<= 1) {
    const int tv = (t >= d) ? sh[t - d] : 0;
    __syncthreads();
    sh[t] += tv;
    __syncthreads();
  }
  blkhist[(size_t)t * NBINS + bin] = sh[t] - v;  // exclusive prefix over blocks
  if (t == NB - 1) bintot[bin] = sh[t];
}

__global__ __launch_bounds__(512) void scan_bins(const int* __restrict__ bintot,
                                                 int* __restrict__ binbase) {
  __shared__ int sh[512];
  const int t = threadIdx.x;
  const int v = (t < NBINS) ? bintot[t] : 0;
  sh[t] = v;
  __syncthreads();
  for (int d = 1; d < 512; d <<= 1) {
    const int tv = (t >= d) ? sh[t - d] : 0;
    __syncthreads();
    sh[t] += tv;
    __syncthreads();
  }
  if (t < NBINS) binbase[t] = sh[t] - v;
  if (t == NBINS - 1) binbase[NBINS] = sh[t];
}

__global__ __launch_bounds__(256) void bin_scatter(const int* __restrict__ erow,
                                                   const int* __restrict__ ecol,
                                                   const int* __restrict__ blkhist,
                                                   const int* __restrict__ binbase,
                                                   unsigned* __restrict__ benc) {
  __shared__ int cur[NBINS];
  const int blk = blockIdx.x, tid = threadIdx.x;
  for (int i = tid; i < NBINS; i += 256)
    cur[i] = binbase[i] + blkhist[(size_t)blk * NBINS + i];
  __syncthreads();
  const int e0 = blk * CHUNK, e1 = e0 + CHUNK;
  for (int e = e0 + tid; e < e1; e += 256) {
    const int c = ecol[e];
    const unsigned enc = (unsigned)erow[e] | ((unsigned)(c & 255) << 24);
    const int p = atomicAdd(&cur[c >> 8], 1);
    benc[p] = enc;
  }
}

// B: per-bin CSR build with per-dest SOURCE-RANGE sub-sort (src>>13, 13 ranges).
// brow ends up grouped by dest, ascending source-range within each dest ->
// concurrent gather waves share a ~2MB instantaneous working set (L2-fits).
__global__ __launch_bounds__(256) void bin_build(const unsigned* __restrict__ benc,
                                                 const int* __restrict__ binbase,
                                                 int* __restrict__ brow,
                                                 int* __restrict__ offs,
                                                 float* __restrict__ dinv) {
  __shared__ int hist[256 * NRANGE];  // 13KB: count -> cursor (in place)
  __shared__ int sh[256];
  const int b = blockIdx.x, tid = threadIdx.x;
  const int e0 = binbase[b], e1 = binbase[b + 1];
  for (int i = tid; i < 256 * NRANGE; i += 256) hist[i] = 0;
  __syncthreads();
  for (int e = e0 + tid; e < e1; e += 256) {
    const unsigned v = benc[e];
    const int key = (int)(v >> 24) * NRANGE + (int)((v & 0x00FFFFFFu) >> RSH);
    atomicAdd(&hist[key], 1);
  }
  __syncthreads();
  // per-dest serial exclusive prefix over its NRANGE counters; total = degree
  const int base = tid * NRANGE;
  int d0 = 0;
#pragma unroll
  for (int r = 0; r < NRANGE; ++r) {
    const int c = hist[base + r];
    hist[base + r] = d0;
    d0 += c;
  }
  sh[tid] = d0;
  __syncthreads();
  for (int d = 1; d < 256; d <<= 1) {
    const int tv = (tid >= d) ? sh[tid - d] : 0;
    __syncthreads();
    sh[tid] += tv;
    __syncthreads();
  }
  const int myoff = e0 + sh[tid] - d0;  // global CSR offset for node (b<<8)+tid
#pragma unroll
  for (int r = 0; r < NRANGE; ++r) hist[base + r] += myoff;  // -> cursors
  const int node = (b << 8) + tid;
  if (node < N_NODES) {
    offs[node] = myoff;
    dinv[node] = rsqrtf((float)d0 + 1.0f);
  }
  if (b == NBINS - 1 && tid == 255) offs[N_NODES] = e1;
  __syncthreads();
  for (int e = e0 + tid; e < e1; e += 256) {
    const unsigned v = benc[e];
    const int src = (int)(v & 0x00FFFFFFu);
    const int key = (int)(v >> 24) * NRANGE + (src >> RSH);
    const int p = atomicAdd(&hist[key], 1);
    brow[p] = src;
  }
}

// ------- gather: one wave per node, 16-deep in-flight gathers -------------
__global__ __launch_bounds__(256) void gather_out(const unsigned short* __restrict__ xwb,
                                                  const float* __restrict__ dinv,
                                                  const int* __restrict__ offs,
                                                  const int* __restrict__ brow,
                                                  const float* __restrict__ bias,
                                                  float* __restrict__ out) {
  const int lane = threadIdx.x & 63;
  const int node = blockIdx.x * (blockDim.x >> 6) + (threadIdx.x >> 6);
  if (node >= N_NODES) return;
  const float di = dinv[node];
  const int c0 = lane * 2;

  auto ld2 = [&](int r) -> float2 {
    const unsigned v = *reinterpret_cast<const unsigned*>(&xwb[(size_t)r * OUT_DIM + c0]);
    float2 f;
    f.x = __builtin_bit_cast(float, v << 16);
    f.y = __builtin_bit_cast(float, v & 0xFFFF0000u);
    return f;
  };

  float2 acc = ld2(node);  // self-loop (prescaled)
  float2 acc2 = make_float2(0.f, 0.f);

  int e = offs[node];
  const int e1 = offs[node + 1];
  for (; e + 16 <= e1; e += 16) {
    int r[16];
#pragma unroll
    for (int i = 0; i < 16; ++i) r[i] = brow[e + i];
    float2 v[16];
#pragma unroll
    for (int i = 0; i < 16; ++i) v[i] = ld2(r[i]);
#pragma unroll
    for (int i = 0; i < 16; i += 2) {
      acc.x += v[i].x + v[i + 1].x;
      acc.y += v[i].y + v[i + 1].y;
    }
  }
  for (; e + 4 <= e1; e += 4) {
    const int r0 = brow[e], r1 = brow[e + 1], r2 = brow[e + 2], r3 = brow[e + 3];
    const float2 v0 = ld2(r0), v1 = ld2(r1), v2 = ld2(r2), v3 = ld2(r3);
    acc2.x += (v0.x + v1.x) + (v2.x + v3.x);
    acc2.y += (v0.y + v1.y) + (v2.y + v3.y);
  }
  for (; e < e1; ++e) {
    const float2 v = ld2(brow[e]);
    acc2.x += v.x;
    acc2.y += v.y;
  }
  acc.x += acc2.x;
  acc.y += acc2.y;

  const float2 bb = *reinterpret_cast<const float2*>(&bias[c0]);
  float2 o;
  o.x = acc.x * di + bb.x;
  o.y = acc.y * di + bb.y;
  *reinterpret_cast<float2*>(&out[(size_t)node * OUT_DIM + c0]) = o;
}

extern "C" void kernel_launch(void* const* d_in, const int* in_sizes, int n_in,
                              void* d_out, int out_size, void* d_ws, size_t ws_size,
                              hipStream_t stream) {
  const float* x    = (const float*)d_in[0];
  const int*   eidx = (const int*)d_in[1];
  const float* W    = (const float*)d_in[2];
  const float* b    = (const float*)d_in[3];
  float* out = (float*)d_out;

  const int* erow = eidx;            // sources
  const int* ecol = eidx + N_EDGES;  // destinations

  char* ws = (char*)d_ws;
  size_t off = 0;
  auto alloc = [&](size_t bytes) -> void* {
    void* p = ws + off;
    off = (off + bytes + 255) & ~(size_t)255;
    return p;
  };
  unsigned short* xwb = (unsigned short*)alloc((size_t)N_NODES * OUT_DIM * sizeof(short)); // 25.6MB
  short* WT      = (short*)alloc((size_t)OUT_DIM * IN_DIM * sizeof(short));    // 128KB
  float* dinv    = (float*)alloc((size_t)N_NODES * sizeof(float));             // 400KB
  int*   offs    = (int*)alloc((size_t)(N_NODES + 1) * sizeof(int));           // 400KB
  int*   blkhist = (int*)alloc((size_t)NB * NBINS * sizeof(int));              // 1.6MB
  int*   bintot  = (int*)alloc((size_t)NBINS * sizeof(int));
  int*   binbase = (int*)alloc((size_t)(NBINS + 1) * sizeof(int));
  int*   brow    = (int*)alloc((size_t)N_EDGES * sizeof(int));                 // 12.8MB
  unsigned* benc = (unsigned*)alloc((size_t)N_EDGES * sizeof(unsigned));       // 12.8MB

  cast_WT<<<256, 256, 0, stream>>>(W, WT);

  bin_count<<<NB, 256, 0, stream>>>(ecol, blkhist);
  scan_blkhist<<<NBINS, NB, 0, stream>>>(blkhist, bintot);
  scan_bins<<<1, 512, 0, stream>>>(bintot, binbase);
  bin_scatter<<<NB, 256, 0, stream>>>(erow, ecol, blkhist, binbase, benc);
  bin_build<<<NBINS, 256, 0, stream>>>(benc, binbase, brow, offs, dinv);

  gemm_lds<<<(N_NODES + 127) / 128, 256, 0, stream>>>(x, WT, dinv, xwb);
  gather_out<<<(N_NODES + 3) / 4, 256, 0, stream>>>(xwb, dinv, offs, brow, b, out);
}

// Round 19
// 263.028 us; speedup vs baseline: 1.3733x; 1.0941x over previous
//
#include <hip/hip_runtime.h>
#include <hip/hip_bf16.h>

using short8  = __attribute__((ext_vector_type(8))) short;
using f32x4   = __attribute__((ext_vector_type(4))) float;
using uint32x4 = __attribute__((ext_vector_type(4))) unsigned;

static constexpr int N_NODES = 100000;
static constexpr int N_EDGES = 3200000;
static constexpr int IN_DIM  = 512;
static constexpr int OUT_DIM = 128;
static constexpr int NBINS   = (N_NODES + 255) / 256;  // 391 bins of 256 nodes
static constexpr int NB      = 1024;                   // binning blocks
static constexpr int CHUNK   = N_EDGES / NB;           // 3125 edges/block (exact)
static constexpr int EPB     = (CHUNK + 255) / 256;    // 13 edges/thread
static constexpr int SLACK   = 9216;                   // bin capacity (8186+6sigma=8724)
static constexpr int RSH     = 13;                     // source-range shift
static constexpr int NRANGE  = (N_NODES + (1 << RSH) - 1) >> RSH;  // 13

__device__ __forceinline__ short f2bf(float f) {
  unsigned u = __builtin_bit_cast(unsigned, f);
  u = (u + 0x7FFFu + ((u >> 16) & 1u)) >> 16;  // RNE
  return (short)u;
}

__device__ __forceinline__ void gload16(const void* g, void* l) {
  __builtin_amdgcn_global_load_lds(
      (const __attribute__((address_space(1))) unsigned int*)g,
      (__attribute__((address_space(3))) unsigned int*)l, 16, 0, 0);
}

// ------- W [512][128] f32 -> WT [128][512] bf16; also init bin cursors ----
__global__ __launch_bounds__(256) void cast_WT(const float* __restrict__ W,
                                               short* __restrict__ WT,
                                               int* __restrict__ cursor) {
  const int idx = blockIdx.x * 256 + threadIdx.x;  // 65536 total
  if (idx < NBINS) cursor[idx] = idx * SLACK;
  const int c = idx >> 9, k = idx & 511;
  WT[(size_t)c * 512 + k] = f2bf(W[(size_t)k * 128 + c]);
}

// ------------- m97-style LDS GEMM: xwb = (x@W)*dinv, bf16 out -------------
__global__ __launch_bounds__(256) void gemm_lds(const float* __restrict__ x,
                                                const short* __restrict__ WT,
                                                const float* __restrict__ dinv,
                                                unsigned short* __restrict__ xwb) {
  __shared__ float          Abuf[2][128 * 32];  // 2 x 16KB
  __shared__ unsigned short Bbuf[2][128 * 32];  // 2 x 8KB
  const int tid = threadIdx.x;
  const int w   = tid >> 6;
  const int l   = tid & 63;
  const int wr  = w >> 1, wc = w & 1;
  const int lr  = l & 15;
  const int lk  = l >> 4;
  const int row0 = blockIdx.x * 128;
  const char* xb  = reinterpret_cast<const char*>(x);
  const char* wtb = reinterpret_cast<const char*>(WT);
  const int wbase = (tid & ~63) * 16;  // wave-uniform LDS chunk base (bytes)

  auto stage = [&](int kb, int buf) {
#pragma unroll
    for (int t = 0; t < 4; ++t) {
      const int f = t * 256 + tid;  // unit index 0..1023
      const int r = f >> 3;
      const int u = f & 7;
      const int grow = min(row0 + r, N_NODES - 1);
      const char* src = xb + (size_t)grow * 2048 + kb * 128 + ((u ^ (r & 7)) << 4);
      gload16(src, (char*)Abuf[buf] + t * 4096 + wbase);
    }
#pragma unroll
    for (int t = 0; t < 2; ++t) {
      const int f = t * 256 + tid;  // unit index 0..511
      const int c = f >> 2;
      const int u = f & 3;
      const char* src = wtb + (size_t)c * 1024 + kb * 64 + ((u ^ (c & 3)) << 4);
      gload16(src, (char*)Bbuf[buf] + t * 4096 + wbase);
    }
  };

  auto cvt2 = [](float lo, float hi) -> unsigned {
    __hip_bfloat162 h = __float22bfloat162_rn(make_float2(lo, hi));
    unsigned r;
    __builtin_memcpy(&r, &h, 4);
    return r;
  };

  f32x4 acc[4][4] = {};

  auto compute = [&](int buf) {
    const char* Ab = (const char*)Abuf[buf];
    const char* Bb = (const char*)Bbuf[buf];
    short8 a[4], b[4];
#pragma unroll
    for (int rf = 0; rf < 4; ++rf) {
      const int rl = wr * 64 + rf * 16 + lr;
      const char* base = Ab + rl * 128;
      const f32x4 r0 = *(const f32x4*)(base + (((2 * lk)     ^ (rl & 7)) << 4));
      const f32x4 r1 = *(const f32x4*)(base + (((2 * lk + 1) ^ (rl & 7)) << 4));
      uint32x4 ua;
      ua[0] = cvt2(r0[0], r0[1]);
      ua[1] = cvt2(r0[2], r0[3]);
      ua[2] = cvt2(r1[0], r1[1]);
      ua[3] = cvt2(r1[2], r1[3]);
      a[rf] = __builtin_bit_cast(short8, ua);
    }
#pragma unroll
    for (int cf = 0; cf < 4; ++cf) {
      const int cl = wc * 64 + cf * 16 + lr;
      b[cf] = *(const short8*)(Bb + cl * 64 + ((lk ^ (cl & 3)) << 4));
    }
#pragma unroll
    for (int rf = 0; rf < 4; ++rf)
#pragma unroll
      for (int cf = 0; cf < 4; ++cf)
        acc[rf][cf] = __builtin_amdgcn_mfma_f32_16x16x32_bf16(a[rf], b[cf], acc[rf][cf], 0, 0, 0);
  };

  stage(0, 0);
  __syncthreads();
  for (int kb = 0; kb < 16; ++kb) {
    if (kb < 15) stage(kb + 1, (kb + 1) & 1);
    compute(kb & 1);
    __syncthreads();
  }

#pragma unroll
  for (int rf = 0; rf < 4; ++rf) {
#pragma unroll
    for (int j = 0; j < 4; ++j) {
      const int row = row0 + wr * 64 + rf * 16 + lk * 4 + j;
      if (row < N_NODES) {
        const float sc = dinv[row];  // prescale: xwb = xw * dinv[row]
        unsigned short* o = &xwb[(size_t)row * OUT_DIM + wc * 64 + lr];
#pragma unroll
        for (int cf = 0; cf < 4; ++cf)
          o[cf * 16] = (unsigned short)f2bf(acc[rf][cf][j] * sc);
      }
    }
  }
}

// ==== fused binning: LDS histogram + bulk atomic reserve + scatter ========
// Bins are slack-allocated (SLACK slots each) so no global scan is needed.
__global__ __launch_bounds__(256) void bin_scatter(const int* __restrict__ erow,
                                                   const int* __restrict__ ecol,
                                                   int* __restrict__ cursor,
                                                   unsigned* __restrict__ benc) {
  __shared__ int hist[NBINS];
  __shared__ int cur[NBINS];
  const int blk = blockIdx.x, tid = threadIdx.x;
  const int e0 = blk * CHUNK;
  for (int i = tid; i < NBINS; i += 256) hist[i] = 0;
  __syncthreads();

  int cc[EPB], rr[EPB];
#pragma unroll
  for (int i = 0; i < EPB; ++i) {
    const int e = e0 + tid + i * 256;
    const bool ok = (tid + i * 256) < CHUNK;
    cc[i] = ok ? ecol[e] : -1;
    rr[i] = ok ? erow[e] : 0;
    if (ok) atomicAdd(&hist[cc[i] >> 8], 1);
  }
  __syncthreads();
  for (int i = tid; i < NBINS; i += 256)
    cur[i] = hist[i] ? atomicAdd(&cursor[i], hist[i]) : 0;
  __syncthreads();
#pragma unroll
  for (int i = 0; i < EPB; ++i) {
    if (cc[i] >= 0) {
      const unsigned enc = (unsigned)rr[i] | ((unsigned)(cc[i] & 255) << 24);
      const int p = atomicAdd(&cur[cc[i] >> 8], 1);
      benc[p] = enc;
    }
  }
}

// B: per-bin CSR build (padded segments) with per-dest source-range sub-sort.
__global__ __launch_bounds__(256) void bin_build(const unsigned* __restrict__ benc,
                                                 const int* __restrict__ cursor,
                                                 int* __restrict__ brow,
                                                 int* __restrict__ offs,
                                                 int* __restrict__ oend,
                                                 float* __restrict__ dinv) {
  __shared__ int hist[256 * NRANGE];  // 13KB: count -> cursor (in place)
  __shared__ int sh[256];
  const int b = blockIdx.x, tid = threadIdx.x;
  const int e0 = b * SLACK;
  const int e1 = cursor[b];  // e0 + count_b
  for (int i = tid; i < 256 * NRANGE; i += 256) hist[i] = 0;
  __syncthreads();
  for (int e = e0 + tid; e < e1; e += 256) {
    const unsigned v = benc[e];
    const int key = (int)(v >> 24) * NRANGE + (int)((v & 0x00FFFFFFu) >> RSH);
    atomicAdd(&hist[key], 1);
  }
  __syncthreads();
  // per-dest serial exclusive prefix over its NRANGE counters; total = degree
  const int base = tid * NRANGE;
  int d0 = 0;
#pragma unroll
  for (int r = 0; r < NRANGE; ++r) {
    const int c = hist[base + r];
    hist[base + r] = d0;
    d0 += c;
  }
  sh[tid] = d0;
  __syncthreads();
  for (int d = 1; d < 256; d <<= 1) {
    const int tv = (tid >= d) ? sh[tid - d] : 0;
    __syncthreads();
    sh[tid] += tv;
    __syncthreads();
  }
  const int myoff = e0 + sh[tid] - d0;  // padded CSR offset for node (b<<8)+tid
#pragma unroll
  for (int r = 0; r < NRANGE; ++r) hist[base + r] += myoff;  // -> cursors
  const int node = (b << 8) + tid;
  if (node < N_NODES) {
    offs[node] = myoff;
    oend[node] = myoff + d0;
    dinv[node] = rsqrtf((float)d0 + 1.0f);
  }
  __syncthreads();
  for (int e = e0 + tid; e < e1; e += 256) {
    const unsigned v = benc[e];
    const int src = (int)(v & 0x00FFFFFFu);
    const int key = (int)(v >> 24) * NRANGE + (src >> RSH);
    const int p = atomicAdd(&hist[key], 1);
    brow[p] = src;
  }
}

// ------- gather: one wave per node, 16-deep in-flight gathers -------------
__global__ __launch_bounds__(256) void gather_out(const unsigned short* __restrict__ xwb,
                                                  const float* __restrict__ dinv,
                                                  const int* __restrict__ offs,
                                                  const int* __restrict__ oend,
                                                  const int* __restrict__ brow,
                                                  const float* __restrict__ bias,
                                                  float* __restrict__ out) {
  const int lane = threadIdx.x & 63;
  const int node = blockIdx.x * (blockDim.x >> 6) + (threadIdx.x >> 6);
  if (node >= N_NODES) return;
  const float di = dinv[node];
  const int c0 = lane * 2;

  auto ld2 = [&](int r) -> float2 {
    const unsigned v = *reinterpret_cast<const unsigned*>(&xwb[(size_t)r * OUT_DIM + c0]);
    float2 f;
    f.x = __builtin_bit_cast(float, v << 16);
    f.y = __builtin_bit_cast(float, v & 0xFFFF0000u);
    return f;
  };

  float2 acc = ld2(node);  // self-loop (prescaled)
  float2 acc2 = make_float2(0.f, 0.f);

  int e = offs[node];
  const int e1 = oend[node];
  for (; e + 16 <= e1; e += 16) {
    int r[16];
#pragma unroll
    for (int i = 0; i < 16; ++i) r[i] = brow[e + i];
    float2 v[16];
#pragma unroll
    for (int i = 0; i < 16; ++i) v[i] = ld2(r[i]);
#pragma unroll
    for (int i = 0; i < 16; i += 2) {
      acc.x += v[i].x + v[i + 1].x;
      acc.y += v[i].y + v[i + 1].y;
    }
  }
  for (; e + 4 <= e1; e += 4) {
    const int r0 = brow[e], r1 = brow[e + 1], r2 = brow[e + 2], r3 = brow[e + 3];
    const float2 v0 = ld2(r0), v1 = ld2(r1), v2 = ld2(r2), v3 = ld2(r3);
    acc2.x += (v0.x + v1.x) + (v2.x + v3.x);
    acc2.y += (v0.y + v1.y) + (v2.y + v3.y);
  }
  for (; e < e1; ++e) {
    const float2 v = ld2(brow[e]);
    acc2.x += v.x;
    acc2.y += v.y;
  }
  acc.x += acc2.x;
  acc.y += acc2.y;

  const float2 bb = *reinterpret_cast<const float2*>(&bias[c0]);
  float2 o;
  o.x = acc.x * di + bb.x;
  o.y = acc.y * di + bb.y;
  *reinterpret_cast<float2*>(&out[(size_t)node * OUT_DIM + c0]) = o;
}

extern "C" void kernel_launch(void* const* d_in, const int* in_sizes, int n_in,
                              void* d_out, int out_size, void* d_ws, size_t ws_size,
                              hipStream_t stream) {
  const float* x    = (const float*)d_in[0];
  const int*   eidx = (const int*)d_in[1];
  const float* W    = (const float*)d_in[2];
  const float* b    = (const float*)d_in[3];
  float* out = (float*)d_out;

  const int* erow = eidx;            // sources
  const int* ecol = eidx + N_EDGES;  // destinations

  char* ws = (char*)d_ws;
  size_t off = 0;
  auto alloc = [&](size_t bytes) -> void* {
    void* p = ws + off;
    off = (off + bytes + 255) & ~(size_t)255;
    return p;
  };
  unsigned short* xwb = (unsigned short*)alloc((size_t)N_NODES * OUT_DIM * sizeof(short)); // 25.6MB
  short* WT      = (short*)alloc((size_t)OUT_DIM * IN_DIM * sizeof(short));    // 128KB
  float* dinv    = (float*)alloc((size_t)N_NODES * sizeof(float));             // 400KB
  int*   offs    = (int*)alloc((size_t)N_NODES * sizeof(int));                 // 400KB
  int*   oend    = (int*)alloc((size_t)N_NODES * sizeof(int));                 // 400KB
  int*   cursor  = (int*)alloc((size_t)NBINS * sizeof(int));
  int*   brow    = (int*)alloc((size_t)NBINS * SLACK * sizeof(int));           // 14.4MB
  unsigned* benc = (unsigned*)alloc((size_t)NBINS * SLACK * sizeof(unsigned)); // 14.4MB

  cast_WT<<<256, 256, 0, stream>>>(W, WT, cursor);
  bin_scatter<<<NB, 256, 0, stream>>>(erow, ecol, cursor, benc);
  bin_build<<<NBINS, 256, 0, stream>>>(benc, cursor, brow, offs, oend, dinv);
  gemm_lds<<<(N_NODES + 127) / 128, 256, 0, stream>>>(x, WT, dinv, xwb);
  gather_out<<<(N_NODES + 3) / 4, 256, 0, stream>>>(xwb, dinv, offs, oend, brow, b, out);
}